// Round 1
// 198.108 us; speedup vs baseline: 1.0095x; 1.0095x over previous
//
#include <hip/hip_runtime.h>
#include <math.h>

#define B_CONST 256
#define V_CONST 128000           // 32000 float4 per row
#define L_CONST 200
#define SLICES  25               // 1280 float4 per slice-block; 5 float4 per thread

typedef float f32x4 __attribute__((ext_vector_type(4)));

// ws layout: int partial[SLICES*B], int sub[B], int dist[B]

__global__ __launch_bounds__(256) void rank_count_kernel(
    const float* __restrict__ scores,
    const int* __restrict__ labels,
    const int* __restrict__ seqs,
    int* __restrict__ partial,
    int* __restrict__ sub,
    int* __restrict__ dist)
{
    const int slice = blockIdx.x;
    const int b     = blockIdx.y;
    const int tid   = threadIdx.x;
    const int wave  = tid >> 6;

    const float* row = scores + (size_t)b * V_CONST;

    // Issue the 5 independent streaming loads FIRST. Non-temporal: scores is
    // strictly read-once (131 MB streamed through 4 MiB/XCD L2 per iteration;
    // the harness's 500 MiB poison fill evicts L3 between iterations anyway),
    // so skip cache allocation on this path.
    const f32x4* row4 = (const f32x4*)row;
    const int base = slice * 1280 + tid;     // f4 units
    f32x4 a0 = __builtin_nontemporal_load(row4 + base);
    f32x4 a1 = __builtin_nontemporal_load(row4 + base + 256);
    f32x4 a2 = __builtin_nontemporal_load(row4 + base + 512);
    f32x4 a3 = __builtin_nontemporal_load(row4 + base + 768);
    f32x4 a4 = __builtin_nontemporal_load(row4 + base + 1024);

    // predict is re-read by all 25 slice-blocks of this row: keep it cached.
    const float predict = row[labels[b]];

    __shared__ int s_seq[L_CONST];
    __shared__ int s_wcnt[4];
    __shared__ int s_wsub[4];
    __shared__ int s_wdist[4];

    int myseq = 0;
    float sv = 0.0f;
    if (slice == 0 && tid < L_CONST) {
        myseq = seqs[b * L_CONST + tid];
        s_seq[tid] = myseq;
        sv = row[myseq];                     // gather issued early, from register
    }

    int cnt = 0;
    cnt += (a0[0] > predict) + (a0[1] > predict) + (a0[2] > predict) + (a0[3] > predict);
    cnt += (a1[0] > predict) + (a1[1] > predict) + (a1[2] > predict) + (a1[3] > predict);
    cnt += (a2[0] > predict) + (a2[1] > predict) + (a2[2] > predict) + (a2[3] > predict);
    cnt += (a3[0] > predict) + (a3[1] > predict) + (a3[2] > predict) + (a3[3] > predict);
    cnt += (a4[0] > predict) + (a4[1] > predict) + (a4[2] > predict) + (a4[3] > predict);

    // wave64 shuffle reduce; wave leaders store directly (no LDS atomics, no
    // zero-init barrier).
    #pragma unroll
    for (int off = 32; off > 0; off >>= 1)
        cnt += __shfl_down(cnt, off, 64);
    if ((tid & 63) == 0) s_wcnt[wave] = cnt;

    __syncthreads();                         // s_seq + s_wcnt visible

    if (slice == 0) {
        // history correction: dedup via LDS, per-thread flags, wave reduce
        int idist = 0, isub = 0;
        if (tid < L_CONST) {
            bool first = true;
            for (int j = 0; j < tid; ++j) {
                if (s_seq[j] == myseq) { first = false; break; }
            }
            if (first) {
                idist = 1;
                if (sv > predict) isub = 1;
            }
        }
        #pragma unroll
        for (int off = 32; off > 0; off >>= 1) {
            idist += __shfl_down(idist, off, 64);
            isub  += __shfl_down(isub,  off, 64);
        }
        if ((tid & 63) == 0) { s_wsub[wave] = isub; s_wdist[wave] = idist; }
        __syncthreads();                     // uniform within slice-0 blocks
        if (tid == 0) {
            sub[b]  = s_wsub[0] + s_wsub[1] + s_wsub[2] + s_wsub[3];
            dist[b] = s_wdist[0] + s_wdist[1] + s_wdist[2] + s_wdist[3];
        }
    }

    if (tid == 0)
        partial[slice * B_CONST + b] = s_wcnt[0] + s_wcnt[1] + s_wcnt[2] + s_wcnt[3];
}

// single wave, 64 threads, 4 rows per lane, zero barriers
__global__ __launch_bounds__(64) void finalize_kernel(
    const int* __restrict__ partial,
    const int* __restrict__ sub,
    const int* __restrict__ dist,
    float* __restrict__ out)
{
    const int l = threadIdx.x;               // 0..63

    float acc[12];
    #pragma unroll
    for (int q = 0; q < 12; ++q) acc[q] = 0.0f;

    const float ks[5] = {1.0f, 5.0f, 10.0f, 20.0f, 50.0f};

    #pragma unroll
    for (int r = 0; r < 4; ++r) {
        const int b = l + 64 * r;            // coalesced within the wave
        int gt = 0;
        #pragma unroll
        for (int s = 0; s < SLICES; ++s) gt += partial[s * B_CONST + b];
        const float rank  = (float)(gt - sub[b]);
        const float valid = (float)(V_CONST - dist[b]);

        const float invlog = 1.0f / log2f(rank + 2.0f);
        #pragma unroll
        for (int i = 0; i < 5; ++i) {
            const float ind = (rank < ks[i]) ? 1.0f : 0.0f;
            acc[2 * i]     += ind * invlog;  // NDCG@k
            acc[2 * i + 1] += ind;           // Recall@k
        }
        acc[10] += 1.0f / (rank + 1.0f);     // MRR
        acc[11] += 1.0f - rank / valid;      // AUC-like
    }

    #pragma unroll
    for (int q = 0; q < 12; ++q) {
        float v = acc[q];
        #pragma unroll
        for (int off = 32; off > 0; off >>= 1)
            v += __shfl_down(v, off, 64);
        if (l == 0) out[q] = v * (1.0f / B_CONST);
    }
    if (l == 0) out[12] = 0.0f;
}

extern "C" void kernel_launch(void* const* d_in, const int* in_sizes, int n_in,
                              void* d_out, int out_size, void* d_ws, size_t ws_size,
                              hipStream_t stream) {
    const float* scores = (const float*)d_in[0];
    const int*   labels = (const int*)d_in[1];
    const int*   seqs   = (const int*)d_in[2];
    float* out = (float*)d_out;
    int*   ws  = (int*)d_ws;

    int* partial = ws;                               // SLICES*B
    int* sub     = ws + SLICES * B_CONST;            // B
    int* dist    = ws + SLICES * B_CONST + B_CONST;  // B

    rank_count_kernel<<<dim3(SLICES, B_CONST), 256, 0, stream>>>(
        scores, labels, seqs, partial, sub, dist);
    finalize_kernel<<<1, 64, 0, stream>>>(partial, sub, dist, out);
}

// Round 2
// 195.882 us; speedup vs baseline: 1.0210x; 1.0114x over previous
//
#include <hip/hip_runtime.h>
#include <math.h>

#define B_CONST 256
#define V_CONST 128000           // 32000 float4 per row
#define L_CONST 200
#define SLICES  25               // counting tasks per row
#define F4_PER_SLICE 1280        // 32000 / 25
#define F4_PER_LANE  20          // 1280 / 64

typedef float f32x4 __attribute__((ext_vector_type(4)));

// ws layout: int partial[SLICES*B], int sub[B], int dist[B]

// grid (13, 256), block 128 (= 2 waves). Global wave id within row:
// t = blockIdx.x*2 + (tid>>6), t in 0..25. t<25: counting slice t; t==25: history.
// ZERO barriers, ZERO LDS: each wave is an independent task; counts accumulate
// on the scalar pipe via ballot+popcount.
__global__ __launch_bounds__(128, 4) void rank_count_kernel(
    const float* __restrict__ scores,
    const int* __restrict__ labels,
    const int* __restrict__ seqs,
    int* __restrict__ partial,
    int* __restrict__ sub,
    int* __restrict__ dist)
{
    const int lane = threadIdx.x & 63;
    const int b    = blockIdx.y;
    const int t    = blockIdx.x * 2 + (threadIdx.x >> 6);

    const float* row = scores + (size_t)b * V_CONST;

    // uniform scalar chain (s_load): labels[b] -> row[label]; issued first so
    // its latency hides under the vector loads below.
    const float predict = row[labels[b]];

    if (t < SLICES) {
        // ---- streaming count wave: 20 KB contiguous, all 20 loads in flight
        const f32x4* row4 = (const f32x4*)row;
        const int base = t * F4_PER_SLICE + lane;
        f32x4 v[F4_PER_LANE];
        #pragma unroll
        for (int k = 0; k < F4_PER_LANE; ++k)
            v[k] = __builtin_nontemporal_load(row4 + base + k * 64);

        // ballot+popcount: v_cmp (VALU) + s_bcnt1/s_add (scalar pipe, co-issued);
        // no cross-lane shuffle reduce needed — cnt is wave-uniform.
        int cnt = 0;
        #pragma unroll
        for (int k = 0; k < F4_PER_LANE; ++k) {
            cnt += __popcll(__ballot(v[k][0] > predict));
            cnt += __popcll(__ballot(v[k][1] > predict));
            cnt += __popcll(__ballot(v[k][2] > predict));
            cnt += __popcll(__ballot(v[k][3] > predict));
        }
        if (lane == 0) partial[t * B_CONST + b] = cnt;
    } else {
        // ---- history wave: dedup 200 entries in-register via shfl broadcast
        const int* sq = seqs + b * L_CONST;
        int e[4], val[4];
        float sv[4];
        #pragma unroll
        for (int k = 0; k < 4; ++k) {
            e[k]   = lane + 64 * k;
            val[k] = (e[k] < L_CONST) ? sq[e[k]] : -1;          // -1 sentinel
            sv[k]  = (e[k] < L_CONST) ? row[val[k]] : -1.0e30f; // gather early
        }
        bool first[4] = {true, true, true, true};
        #pragma unroll
        for (int jb = 0; jb < 4; ++jb) {
            for (int l = 0; l < 64; ++l) {
                const int j  = jb * 64 + l;
                const int sj = __shfl(val[jb], l);
                #pragma unroll
                for (int k = jb; k < 4; ++k)   // j < e[k] impossible for k < jb
                    if (j < e[k] && sj == val[k]) first[k] = false;
            }
        }
        int d = 0, s = 0;
        #pragma unroll
        for (int k = 0; k < 4; ++k) {
            const bool isdist = first[k] && (e[k] < L_CONST);
            d += __popcll(__ballot(isdist));
            s += __popcll(__ballot(isdist && (sv[k] > predict)));
        }
        if (lane == 0) { dist[b] = d; sub[b] = s; }
    }
}

// single wave, 64 threads, 4 rows per lane, zero barriers
__global__ __launch_bounds__(64) void finalize_kernel(
    const int* __restrict__ partial,
    const int* __restrict__ sub,
    const int* __restrict__ dist,
    float* __restrict__ out)
{
    const int l = threadIdx.x;               // 0..63

    float acc[12];
    #pragma unroll
    for (int q = 0; q < 12; ++q) acc[q] = 0.0f;

    const float ks[5] = {1.0f, 5.0f, 10.0f, 20.0f, 50.0f};

    #pragma unroll
    for (int r = 0; r < 4; ++r) {
        const int b = l + 64 * r;            // coalesced within the wave
        int gt = 0;
        #pragma unroll
        for (int s = 0; s < SLICES; ++s) gt += partial[s * B_CONST + b];
        const float rank  = (float)(gt - sub[b]);
        const float valid = (float)(V_CONST - dist[b]);

        const float invlog = 1.0f / log2f(rank + 2.0f);
        #pragma unroll
        for (int i = 0; i < 5; ++i) {
            const float ind = (rank < ks[i]) ? 1.0f : 0.0f;
            acc[2 * i]     += ind * invlog;  // NDCG@k
            acc[2 * i + 1] += ind;           // Recall@k
        }
        acc[10] += 1.0f / (rank + 1.0f);     // MRR
        acc[11] += 1.0f - rank / valid;      // AUC-like
    }

    #pragma unroll
    for (int q = 0; q < 12; ++q) {
        float v = acc[q];
        #pragma unroll
        for (int off = 32; off > 0; off >>= 1)
            v += __shfl_down(v, off, 64);
        if (l == 0) out[q] = v * (1.0f / B_CONST);
    }
    if (l == 0) out[12] = 0.0f;
}

extern "C" void kernel_launch(void* const* d_in, const int* in_sizes, int n_in,
                              void* d_out, int out_size, void* d_ws, size_t ws_size,
                              hipStream_t stream) {
    const float* scores = (const float*)d_in[0];
    const int*   labels = (const int*)d_in[1];
    const int*   seqs   = (const int*)d_in[2];
    float* out = (float*)d_out;
    int*   ws  = (int*)d_ws;

    int* partial = ws;                               // SLICES*B
    int* sub     = ws + SLICES * B_CONST;            // B
    int* dist    = ws + SLICES * B_CONST + B_CONST;  // B

    rank_count_kernel<<<dim3(13, B_CONST), 128, 0, stream>>>(
        scores, labels, seqs, partial, sub, dist);
    finalize_kernel<<<1, 64, 0, stream>>>(partial, sub, dist, out);
}